// Round 8
// baseline (500.372 us; speedup 1.0000x reference)
//
#include <hip/hip_runtime.h>
#include <math.h>

// Problem constants
#define BATCH 8
#define CH 256
#define HH 45
#define WW 80
#define HW 3600        // 45*80
#define PTOT 28800     // BATCH*HW

typedef unsigned short u16;
typedef unsigned int   u32;
typedef __attribute__((ext_vector_type(8))) short bf16x8;
typedef __attribute__((ext_vector_type(4))) float f32x4;

struct __align__(8) us4 { u16 x, y, z, w; };

__device__ __forceinline__ u16 bf16_rne(float x) {
  u32 u = __float_as_uint(x);
  u += 0x7FFF + ((u >> 16) & 1);
  return (u16)(u >> 16);
}

// ---------------------------------------------------------------------------
// K0: weight prep (all bf16 transposes)
// ---------------------------------------------------------------------------
__global__ __launch_bounds__(256) void prep_wts(
    const float* __restrict__ conv1_w, const float* __restrict__ off_w,
    const float* __restrict__ dcn_w,
    u16* __restrict__ w1b, u16* __restrict__ wt_offb, u16* __restrict__ wt_b)
{
  int i = blockIdx.x * 256 + threadIdx.x;
  if (i < 256 * 256) {
    w1b[i] = bf16_rne(conv1_w[i]);
  }
  if (i < 9 * 32 * 512) {
    int tap = i >> 14;
    int r   = i & 16383;
    int oc  = r >> 9;
    int c   = r & 511;
    float v = (oc < 27) ? off_w[((size_t)oc * 512 + c) * 9 + tap] : 0.f;
    wt_offb[i] = bf16_rne(v);
  }
  if (i < 9 * 256 * 256) {
    int c = i & 255;
    int oc = (i >> 8) & 255;
    int tap = i >> 16;
    wt_b[i] = bf16_rne(dcn_w[((size_t)oc * 256 + c) * 9 + tap]);
  }
}

// ---------------------------------------------------------------------------
// K1: flip-transpose x -> concat[P][0:256] bf16 (w-flipped NHWC)
// ---------------------------------------------------------------------------
__global__ __launch_bounds__(256) void flip_transpose(
    const float* __restrict__ x, u16* __restrict__ concat)
{
  __shared__ float tile[32][36];
  const int b  = blockIdx.z;
  const int c0 = blockIdx.y * 32;
  const int p0 = blockIdx.x * 32;
  int rem = HW - p0; if (rem > 32) rem = 32;
  const int t = threadIdx.x;
  {
    int c = t >> 3, p4 = (t & 7) * 4;
    if (p4 < rem) {
      float4 v = *(const float4*)(x + ((size_t)b * CH + c0 + c) * HW + p0 + p4);
      *(float4*)&tile[c][p4] = v;
    }
  }
  __syncthreads();
  {
    int r = t >> 3, cq = (t & 7) * 4;
    if (r < rem) {
      int p = p0 + r;
      int h = p / WW, w = p - h * WW;
      int pf = h * WW + (WW - 1 - w);
      us4 o;
      o.x = bf16_rne(tile[cq + 0][r]);
      o.y = bf16_rne(tile[cq + 1][r]);
      o.z = bf16_rne(tile[cq + 2][r]);
      o.w = bf16_rne(tile[cq + 3][r]);
      *(us4*)(concat + ((size_t)b * HW + pf) * 512 + c0 + cq) = o;
    }
  }
}

// ---------------------------------------------------------------------------
// K2: conv1 via MFMA, XCD b-swizzled: grid (232 = 8b x 29 ptiles, 2 octiles).
// ---------------------------------------------------------------------------
__global__ __launch_bounds__(256) void conv1_mfma(
    const u16* __restrict__ concat, const u16* __restrict__ w1b,
    float* __restrict__ out1)
{
  const int t = threadIdx.x;
  const int wv = t >> 6, lane = t & 63;
  const int lr = lane & 15, lk = lane >> 4;
  const int id = blockIdx.x;
  const int b  = id & 7;
  const int pt = id >> 3;                    // 0..28
  const int oc0 = blockIdx.y * 128 + (wv & 1) * 64;
  const int p0  = pt * 128 + (wv >> 1) * 64; // within image

  const u16* bptr[4];
#pragma unroll
  for (int nt = 0; nt < 4; nt++) {
    int pl = p0 + nt * 16 + lr;
    int pc = pl < HW ? pl : HW - 1;
    int h = pc / WW, w = pc - h * WW;
    int pf = b * HW + h * WW + (WW - 1 - w);
    bptr[nt] = concat + (size_t)pf * 512 + lk * 8;
  }
  const u16* aptr = w1b + ((size_t)(oc0 + lr)) * 256 + lk * 8;

  f32x4 acc[4][4];
#pragma unroll
  for (int mt = 0; mt < 4; mt++)
#pragma unroll
    for (int nt = 0; nt < 4; nt++) acc[mt][nt] = (f32x4)0.f;

#pragma unroll
  for (int cc = 0; cc < 8; cc++) {
    bf16x8 af[4], bfv[4];
#pragma unroll
    for (int mt = 0; mt < 4; mt++)
      af[mt] = *(const bf16x8*)(aptr + (size_t)mt * 16 * 256 + cc * 32);
#pragma unroll
    for (int nt = 0; nt < 4; nt++)
      bfv[nt] = *(const bf16x8*)(bptr[nt] + cc * 32);
#pragma unroll
    for (int mt = 0; mt < 4; mt++)
#pragma unroll
      for (int nt = 0; nt < 4; nt++)
        acc[mt][nt] = __builtin_amdgcn_mfma_f32_16x16x32_bf16(
            af[mt], bfv[nt], acc[mt][nt], 0, 0, 0);
  }

#pragma unroll
  for (int mt = 0; mt < 4; mt++) {
    int oc = oc0 + mt * 16 + lk * 4;
#pragma unroll
    for (int nt = 0; nt < 4; nt++) {
      int pl = p0 + nt * 16 + lr;
      if (pl < HW) {
        float* dst = out1 + ((size_t)(b * CH + oc)) * HW + pl;
#pragma unroll
        for (int r = 0; r < 4; r++)
          dst[(size_t)r * HW] = acc[mt][nt][r];
      }
    }
  }
}

// ---------------------------------------------------------------------------
// K3a: per-(c,b)-plane partial sums. grid (256, 8).
// part[(b*CH+c)*2] = sum, +1 = sumsq
// ---------------------------------------------------------------------------
__global__ __launch_bounds__(256) void stats_part(
    const float* __restrict__ src, float* __restrict__ part)
{
  const int c = blockIdx.x, b = blockIdx.y;
  const int t = threadIdx.x;
  const float* p = src + ((size_t)b * CH + c) * HW;
  float s = 0.f, s2 = 0.f;
  for (int i = t; i < HW; i += 256) {
    float v = p[i];
    s += v; s2 += v * v;
  }
  __shared__ float ls[256], ls2[256];
  ls[t] = s; ls2[t] = s2;
  __syncthreads();
  for (int off = 128; off > 0; off >>= 1) {
    if (t < off) { ls[t] += ls[t + off]; ls2[t] += ls2[t + off]; }
    __syncthreads();
  }
  if (t == 0) {
    part[((size_t)b * CH + c) * 2]     = ls[0];
    part[((size_t)b * CH + c) * 2 + 1] = ls2[0];
  }
}

// K3b: finalize: st[c] = mean, st[256+c] = rstd
__global__ __launch_bounds__(256) void stats_fin(
    const float* __restrict__ part, float* __restrict__ st)
{
  const int c = threadIdx.x;
  float s = 0.f, s2 = 0.f;
#pragma unroll
  for (int b = 0; b < BATCH; b++) {
    s  += part[((size_t)b * CH + c) * 2];
    s2 += part[((size_t)b * CH + c) * 2 + 1];
  }
  float m = s / (float)PTOT;
  float var = s2 / (float)PTOT - m * m;
  st[c] = m;
  st[CH + c] = rsqrtf(var + 1e-5f);
}

// ---------------------------------------------------------------------------
// K4: normalize out1 in place (-> xp NCHW f32) and write concat[P][256:512] bf16
// ---------------------------------------------------------------------------
__global__ __launch_bounds__(256) void norm_transpose(
    float* __restrict__ out1, const float* __restrict__ st,
    const float* __restrict__ g, const float* __restrict__ bb,
    u16* __restrict__ concat)
{
  __shared__ float tile[32][36];
  const int b  = blockIdx.z;
  const int c0 = blockIdx.y * 32;
  const int p0 = blockIdx.x * 32;
  int rem = HW - p0; if (rem > 32) rem = 32;
  const int t = threadIdx.x;

  {
    int c  = t >> 3;
    int p4 = (t & 7) * 4;
    int cg = c0 + c;
    float m  = st[cg], rs = st[CH + cg];
    float sc = g[cg] * rs;
    float sh = bb[cg] - m * sc;
    if (p4 < rem) {
      size_t base = ((size_t)b * CH + cg) * HW + p0;
      float4 v = *(const float4*)(out1 + base + p4);
      v.x = v.x * sc + sh; v.y = v.y * sc + sh;
      v.z = v.z * sc + sh; v.w = v.w * sc + sh;
      *(float4*)(out1 + base + p4) = v;
      *(float4*)&tile[c][p4] = v;
    }
  }
  __syncthreads();
  {
    int r  = t >> 3;
    int cq = (t & 7) * 4;
    if (r < rem) {
      us4 o;
      o.x = bf16_rne(tile[cq + 0][r]);
      o.y = bf16_rne(tile[cq + 1][r]);
      o.z = bf16_rne(tile[cq + 2][r]);
      o.w = bf16_rne(tile[cq + 3][r]);
      *(us4*)(concat + ((size_t)b * HW + p0 + r) * 512 + 256 + c0 + cq) = o;
    }
  }
}

// ---------------------------------------------------------------------------
// K5: offset conv via MFMA, tap-split 3-ways; XCD b-swizzled.
// ---------------------------------------------------------------------------
__global__ __launch_bounds__(128) void off_mfma(
    const u16* __restrict__ concat, const u16* __restrict__ wt_offb,
    float* __restrict__ offp3)
{
  const int t = threadIdx.x;
  const int g = blockIdx.y;
  const int wv = t >> 6, lane = t & 63;
  const int lr = lane & 15, lk = lane >> 4;
  const int id = blockIdx.x;
  const int b    = id & 7;
  const int tile = id >> 3;            // 0..112
  int pl = tile * 32 + wv * 16 + lr;   // 0..3615
  const bool pvalid = pl < HW;
  if (!pvalid) pl = HW - 1;
  const int P = b * HW + pl;
  const int h = pl / WW, w = pl - h * WW;

  f32x4 acc[2];
  acc[0] = (f32x4)0.f; acc[1] = (f32x4)0.f;

#pragma unroll 1
  for (int tl = 0; tl < 3; tl++) {
    int tap = g * 3 + tl;
    int dy = tap / 3 - 1, dx = tap % 3 - 1;
    bool valid = ((unsigned)(h + dy) < HH) && ((unsigned)(w + dx) < WW);
    int Ps = valid ? (P + dy * WW + dx) : P;
    const u16* bp = concat + (size_t)Ps * 512 + lk * 8;
    const u16* ap = wt_offb + ((size_t)tap * 32 + lr) * 512 + lk * 8;
#pragma unroll
    for (int cc = 0; cc < 16; cc++) {
      bf16x8 bfv = *(const bf16x8*)(bp + cc * 32);
      if (!valid) bfv = (bf16x8)(short)0;
      bf16x8 af0 = *(const bf16x8*)(ap + cc * 32);
      bf16x8 af1 = *(const bf16x8*)(ap + 16 * 512 + cc * 32);
      acc[0] = __builtin_amdgcn_mfma_f32_16x16x32_bf16(af0, bfv, acc[0], 0, 0, 0);
      acc[1] = __builtin_amdgcn_mfma_f32_16x16x32_bf16(af1, bfv, acc[1], 0, 0, 0);
    }
  }

  if (pvalid) {
#pragma unroll
    for (int mt = 0; mt < 2; mt++) {
      int oc = mt * 16 + lk * 4;
#pragma unroll
      for (int r = 0; r < 4; r++)
        offp3[((size_t)g * 32 + oc + r) * PTOT + P] = acc[mt][r];
    }
  }
}

// ---------------------------------------------------------------------------
// K6: finalize offsets -> bilinear params per (tap, P). Sums 3 tap-group partials.
// ---------------------------------------------------------------------------
__global__ __launch_bounds__(256) void off_finalize(
    const float* __restrict__ offp3, const float* __restrict__ off_b,
    float4* __restrict__ wts4, int4* __restrict__ idx4)
{
  int i = blockIdx.x * 256 + threadIdx.x;
  if (i >= 9 * PTOT) return;
  int k = i / PTOT;
  int P = i - k * PTOT;
  int b = P / HW;
  int p = P - b * HW;
  int h = p / WW;
  int w = p - h * WW;

  float dy = off_b[2 * k], dx = off_b[2 * k + 1], ml = off_b[18 + k];
#pragma unroll
  for (int g = 0; g < 3; g++) {
    const float* base = offp3 + (size_t)g * 32 * PTOT + P;
    dy += base[(size_t)(2 * k    ) * PTOT];
    dx += base[(size_t)(2 * k + 1) * PTOT];
    ml += base[(size_t)(18 + k   ) * PTOT];
  }

  float m = 1.f / (1.f + expf(-ml));
  float ph = dy + (float)(k / 3 - 1) + (float)h;
  float pw = dx + (float)(k % 3 - 1) + (float)w;
  float h0f = floorf(ph), w0f = floorf(pw);
  float lh = ph - h0f, lw = pw - w0f;
  int h0 = (int)h0f, w0 = (int)w0f;
  int h1 = h0 + 1, w1 = w0 + 1;
  float vh0 = (h0 >= 0 && h0 < HH) ? 1.f : 0.f;
  float vh1 = (h1 >= 0 && h1 < HH) ? 1.f : 0.f;
  float vw0 = (w0 >= 0 && w0 < WW) ? 1.f : 0.f;
  float vw1 = (w1 >= 0 && w1 < WW) ? 1.f : 0.f;
  float4 wv;
  wv.x = (1.f - lh) * (1.f - lw) * m * vh0 * vw0;
  wv.y = (1.f - lh) * lw         * m * vh0 * vw1;
  wv.z = lh * (1.f - lw)         * m * vh1 * vw0;
  wv.w = lh * lw                 * m * vh1 * vw1;
  int hc0 = min(max(h0, 0), HH - 1), hc1 = min(max(h1, 0), HH - 1);
  int wc0 = min(max(w0, 0), WW - 1), wc1 = min(max(w1, 0), WW - 1);
  int base = b * HW;
  int4 iv;
  iv.x = (base + hc0 * WW + wc0) * 512 + 256;
  iv.y = (base + hc0 * WW + wc1) * 512 + 256;
  iv.z = (base + hc1 * WW + wc0) * 512 + 256;
  iv.w = (base + hc1 * WW + wc1) * 512 + 256;
  wts4[i] = wv;
  idx4[i] = iv;
}

// ---------------------------------------------------------------------------
// K7: deformable conv via MFMA bf16 — barrier-free, zero-LDS version.
// Grid 904 = 8 b x 113 tiles of 32 pos (b = id&7 XCD swizzle).
// Block = 128 thr (2 waves); wave = 16 pos x 256 oc (acc = 16 f32x4).
// Each lane builds its OWN B-frag in registers: pos = lane&15,
// channels (lane>>4)*8 per chunk; 4 corner loads + bilinear combine.
// Weight frags shared across waves via L1. No __syncthreads anywhere.
// ---------------------------------------------------------------------------
__global__ __launch_bounds__(128) void deform_mfma(
    const u16* __restrict__ concat,
    const float4* __restrict__ wts4, const int4* __restrict__ idx4,
    const u16* __restrict__ wt_b,
    float* __restrict__ d)
{
  const int t    = threadIdx.x;
  const int wv   = t >> 6;           // 0..1
  const int lane = t & 63;
  const int lr = lane & 15, lk = lane >> 4;
  const int id   = blockIdx.x;
  const int b    = id & 7;
  const int tile = id >> 3;          // 0..112
  const int pl   = tile * 32 + wv * 16 + lr;   // this lane's position
  const bool pv  = pl < HW;
  const int plc  = pv ? pl : HW - 1;
  const int Pg   = b * HW + plc;
  const int cofs = lk * 8;

  f32x4 acc[16];
#pragma unroll
  for (int mt = 0; mt < 16; mt++) acc[mt] = (f32x4)0.f;

#pragma unroll 1
  for (int tap = 0; tap < 9; tap++) {
    const int4   iv = idx4[(size_t)tap * PTOT + Pg];
    const float4 wq = wts4[(size_t)tap * PTOT + Pg];
    const u16* wtap = wt_b + (size_t)tap * 65536 + lr * 256 + cofs;

#pragma unroll 2
    for (int cc = 0; cc < 8; cc++) {
      const int c = cc * 32 + cofs;
      uint4 q0 = *(const uint4*)(concat + iv.x + c);
      uint4 q1 = *(const uint4*)(concat + iv.y + c);
      uint4 q2 = *(const uint4*)(concat + iv.z + c);
      uint4 q3 = *(const uint4*)(concat + iv.w + c);
      u32 a0[4] = {q0.x, q0.y, q0.z, q0.w};
      u32 a1[4] = {q1.x, q1.y, q1.z, q1.w};
      u32 a2[4] = {q2.x, q2.y, q2.z, q2.w};
      u32 a3[4] = {q3.x, q3.y, q3.z, q3.w};
      u32 ro[4];
#pragma unroll
      for (int j = 0; j < 4; j++) {
        float lo = wq.x * __uint_as_float(a0[j] << 16);
        float hi = wq.x * __uint_as_float(a0[j] & 0xFFFF0000u);
        lo = fmaf(wq.y, __uint_as_float(a1[j] << 16), lo);
        hi = fmaf(wq.y, __uint_as_float(a1[j] & 0xFFFF0000u), hi);
        lo = fmaf(wq.z, __uint_as_float(a2[j] << 16), lo);
        hi = fmaf(wq.z, __uint_as_float(a2[j] & 0xFFFF0000u), hi);
        lo = fmaf(wq.w, __uint_as_float(a3[j] << 16), lo);
        hi = fmaf(wq.w, __uint_as_float(a3[j] & 0xFFFF0000u), hi);
        ro[j] = (__float_as_uint(lo) >> 16) | (__float_as_uint(hi) & 0xFFFF0000u);
      }
      uint4 rv = make_uint4(ro[0], ro[1], ro[2], ro[3]);
      bf16x8 bfr;
      __builtin_memcpy(&bfr, &rv, 16);

      const u16* wp = wtap + cc * 32;
#pragma unroll
      for (int mt = 0; mt < 16; mt++) {
        bf16x8 af = *(const bf16x8*)(wp + (size_t)mt * 16 * 256);
        acc[mt] = __builtin_amdgcn_mfma_f32_16x16x32_bf16(af, bfr, acc[mt], 0, 0, 0);
      }
    }
  }

  // epilogue: lane holds C col = lr (pos pl), rows lk*4+r per mt-tile
  if (pv) {
#pragma unroll
    for (int mt = 0; mt < 16; mt++) {
      int oc = mt * 16 + lk * 4;
      float* dst = d + ((size_t)(b * CH + oc)) * HW + pl;
#pragma unroll
      for (int r = 0; r < 4; r++)
        dst[(size_t)r * HW] = acc[mt][r];
    }
  }
}

// ---------------------------------------------------------------------------
// K8: final = relu(d*sc + sh + xp), all NCHW, elementwise float4
// ---------------------------------------------------------------------------
__global__ __launch_bounds__(256) void final_nchw(
    const float* __restrict__ d, const float* __restrict__ xp,
    const float* __restrict__ st2, const float* __restrict__ ng,
    const float* __restrict__ nb, float* __restrict__ out)
{
  u32 i4 = blockIdx.x * 256 + threadIdx.x;
  u32 e = i4 * 4;
  int row = (int)(e / HW);
  int c = row & 255;
  float m = st2[c], rs = st2[CH + c];
  float sc = ng[c] * rs;
  float sh = nb[c] - m * sc;
  float4 dv = *(const float4*)(d + e);
  float4 xv = *(const float4*)(xp + e);
  float4 o;
  o.x = dv.x * sc + sh + xv.x;
  o.y = dv.y * sc + sh + xv.y;
  o.z = dv.z * sc + sh + xv.z;
  o.w = dv.w * sc + sh + xv.w;
  o.x = o.x > 0.f ? o.x : 0.f;
  o.y = o.y > 0.f ? o.y : 0.f;
  o.z = o.z > 0.f ? o.z : 0.f;
  o.w = o.w > 0.f ? o.w : 0.f;
  *(float4*)(out + e) = o;
}

// ---------------------------------------------------------------------------
extern "C" void kernel_launch(void* const* d_in, const int* in_sizes, int n_in,
                              void* d_out, int out_size, void* d_ws, size_t ws_size,
                              hipStream_t stream)
{
  const float* x       = (const float*)d_in[0];
  const float* conv1_w = (const float*)d_in[1];
  const float* bn1_g   = (const float*)d_in[2];
  const float* bn1_b   = (const float*)d_in[3];
  const float* off_w   = (const float*)d_in[4];
  const float* off_b   = (const float*)d_in[5];
  const float* dcn_w   = (const float*)d_in[6];
  const float* norm_g  = (const float*)d_in[8];
  const float* norm_b  = (const float*)d_in[9];
  float* out = (float*)d_out;

  char* ws = (char*)d_ws;
  size_t o = 0;
  float* out1    = (float*)(ws + o); o += (size_t)PTOT * CH * 4;       // 29.5 MB (becomes xp NCHW)
  u16*   concat  = (u16*)  (ws + o); o += (size_t)PTOT * 512 * 2;      // 29.5 MB NHWC bf16 [flipx | xp]
  float* dbuf    = (float*)(ws + o); o += (size_t)PTOT * CH * 4;       // 29.5 MB NCHW
  float* offp3   = (float*)(ws + o); o += (size_t)96 * PTOT * 4;       // 11.1 MB
  u16*   wt_b    = (u16*)  (ws + o); o += (size_t)9 * 256 * 256 * 2;   // 1.18 MB
  u16*   wt_offb = (u16*)  (ws + o); o += (size_t)9 * 32 * 512 * 2;    // 0.29 MB
  u16*   w1b     = (u16*)  (ws + o); o += (size_t)256 * 256 * 2;       // 0.13 MB
  float4* wts4   = (float4*)(ws + o); o += (size_t)9 * PTOT * 16;      // 4.15 MB
  int4*   idx4   = (int4*) (ws + o); o += (size_t)9 * PTOT * 16;       // 4.15 MB
  float* st      = (float*)(ws + o); o += 512 * 4;
  float* st2     = (float*)(ws + o); o += 512 * 4;
  float* part    = (float*)(ws + o); o += (size_t)BATCH * CH * 2 * 4;  // 16 KB

  prep_wts<<<2304, 256, 0, stream>>>(conv1_w, off_w, dcn_w, w1b, wt_offb, wt_b);
  flip_transpose<<<dim3(113, 8, 8), 256, 0, stream>>>(x, concat);
  conv1_mfma<<<dim3(232, 2), 256, 0, stream>>>(concat, w1b, out1);
  stats_part<<<dim3(256, 8), 256, 0, stream>>>(out1, part);
  stats_fin<<<1, 256, 0, stream>>>(part, st);
  norm_transpose<<<dim3(113, 8, 8), 256, 0, stream>>>(out1, st, bn1_g, bn1_b, concat);
  off_mfma<<<dim3(904, 3), 128, 0, stream>>>(concat, wt_offb, offp3);
  off_finalize<<<(9 * PTOT + 255) / 256, 256, 0, stream>>>(offp3, off_b, wts4, idx4);
  deform_mfma<<<904, 128, 0, stream>>>(concat, wts4, idx4, wt_b, dbuf);
  stats_part<<<dim3(256, 8), 256, 0, stream>>>(dbuf, part);
  stats_fin<<<1, 256, 0, stream>>>(part, st2);
  final_nchw<<<7200, 256, 0, stream>>>(dbuf, out1, st2, norm_g, norm_b, out);
}

// Round 9
// 303.448 us; speedup vs baseline: 1.6490x; 1.6490x over previous
//
#include <hip/hip_runtime.h>
#include <math.h>

// Problem constants
#define BATCH 8
#define CH 256
#define HH 45
#define WW 80
#define HW 3600        // 45*80
#define PTOT 28800     // BATCH*HW

typedef unsigned short u16;
typedef unsigned int   u32;
typedef __attribute__((ext_vector_type(8))) short bf16x8;
typedef __attribute__((ext_vector_type(4))) float f32x4;

struct __align__(8) us4 { u16 x, y, z, w; };

__device__ __forceinline__ u16 bf16_rne(float x) {
  u32 u = __float_as_uint(x);
  u += 0x7FFF + ((u >> 16) & 1);
  return (u16)(u >> 16);
}

// ---------------------------------------------------------------------------
// K0: weight prep (all bf16 transposes)
// ---------------------------------------------------------------------------
__global__ __launch_bounds__(256) void prep_wts(
    const float* __restrict__ conv1_w, const float* __restrict__ off_w,
    const float* __restrict__ dcn_w,
    u16* __restrict__ w1b, u16* __restrict__ wt_offb, u16* __restrict__ wt_b)
{
  int i = blockIdx.x * 256 + threadIdx.x;
  if (i < 256 * 256) {
    w1b[i] = bf16_rne(conv1_w[i]);
  }
  if (i < 9 * 32 * 512) {
    int tap = i >> 14;
    int r   = i & 16383;
    int oc  = r >> 9;
    int c   = r & 511;
    float v = (oc < 27) ? off_w[((size_t)oc * 512 + c) * 9 + tap] : 0.f;
    wt_offb[i] = bf16_rne(v);
  }
  if (i < 9 * 256 * 256) {
    int c = i & 255;
    int oc = (i >> 8) & 255;
    int tap = i >> 16;
    wt_b[i] = bf16_rne(dcn_w[((size_t)oc * 256 + c) * 9 + tap]);
  }
}

// ---------------------------------------------------------------------------
// K1: flip-transpose x -> concat[P][0:256] bf16 (w-flipped NHWC)
// ---------------------------------------------------------------------------
__global__ __launch_bounds__(256) void flip_transpose(
    const float* __restrict__ x, u16* __restrict__ concat)
{
  __shared__ float tile[32][36];
  const int b  = blockIdx.z;
  const int c0 = blockIdx.y * 32;
  const int p0 = blockIdx.x * 32;
  int rem = HW - p0; if (rem > 32) rem = 32;
  const int t = threadIdx.x;
  {
    int c = t >> 3, p4 = (t & 7) * 4;
    if (p4 < rem) {
      float4 v = *(const float4*)(x + ((size_t)b * CH + c0 + c) * HW + p0 + p4);
      *(float4*)&tile[c][p4] = v;
    }
  }
  __syncthreads();
  {
    int r = t >> 3, cq = (t & 7) * 4;
    if (r < rem) {
      int p = p0 + r;
      int h = p / WW, w = p - h * WW;
      int pf = h * WW + (WW - 1 - w);
      us4 o;
      o.x = bf16_rne(tile[cq + 0][r]);
      o.y = bf16_rne(tile[cq + 1][r]);
      o.z = bf16_rne(tile[cq + 2][r]);
      o.w = bf16_rne(tile[cq + 3][r]);
      *(us4*)(concat + ((size_t)b * HW + pf) * 512 + c0 + cq) = o;
    }
  }
}

// ---------------------------------------------------------------------------
// K2: conv1 via MFMA, XCD b-swizzled: grid (232 = 8b x 29 ptiles, 2 octiles).
// ---------------------------------------------------------------------------
__global__ __launch_bounds__(256) void conv1_mfma(
    const u16* __restrict__ concat, const u16* __restrict__ w1b,
    float* __restrict__ out1)
{
  const int t = threadIdx.x;
  const int wv = t >> 6, lane = t & 63;
  const int lr = lane & 15, lk = lane >> 4;
  const int id = blockIdx.x;
  const int b  = id & 7;
  const int pt = id >> 3;                    // 0..28
  const int oc0 = blockIdx.y * 128 + (wv & 1) * 64;
  const int p0  = pt * 128 + (wv >> 1) * 64; // within image

  const u16* bptr[4];
#pragma unroll
  for (int nt = 0; nt < 4; nt++) {
    int pl = p0 + nt * 16 + lr;
    int pc = pl < HW ? pl : HW - 1;
    int h = pc / WW, w = pc - h * WW;
    int pf = b * HW + h * WW + (WW - 1 - w);
    bptr[nt] = concat + (size_t)pf * 512 + lk * 8;
  }
  const u16* aptr = w1b + ((size_t)(oc0 + lr)) * 256 + lk * 8;

  f32x4 acc[4][4];
#pragma unroll
  for (int mt = 0; mt < 4; mt++)
#pragma unroll
    for (int nt = 0; nt < 4; nt++) acc[mt][nt] = (f32x4)0.f;

#pragma unroll
  for (int cc = 0; cc < 8; cc++) {
    bf16x8 af[4], bfv[4];
#pragma unroll
    for (int mt = 0; mt < 4; mt++)
      af[mt] = *(const bf16x8*)(aptr + (size_t)mt * 16 * 256 + cc * 32);
#pragma unroll
    for (int nt = 0; nt < 4; nt++)
      bfv[nt] = *(const bf16x8*)(bptr[nt] + cc * 32);
#pragma unroll
    for (int mt = 0; mt < 4; mt++)
#pragma unroll
      for (int nt = 0; nt < 4; nt++)
        acc[mt][nt] = __builtin_amdgcn_mfma_f32_16x16x32_bf16(
            af[mt], bfv[nt], acc[mt][nt], 0, 0, 0);
  }

#pragma unroll
  for (int mt = 0; mt < 4; mt++) {
    int oc = oc0 + mt * 16 + lk * 4;
#pragma unroll
    for (int nt = 0; nt < 4; nt++) {
      int pl = p0 + nt * 16 + lr;
      if (pl < HW) {
        float* dst = out1 + ((size_t)(b * CH + oc)) * HW + pl;
#pragma unroll
        for (int r = 0; r < 4; r++)
          dst[(size_t)r * HW] = acc[mt][nt][r];
      }
    }
  }
}

// ---------------------------------------------------------------------------
// K3a: per-(c,b)-plane partial sums. grid (256, 8).
// ---------------------------------------------------------------------------
__global__ __launch_bounds__(256) void stats_part(
    const float* __restrict__ src, float* __restrict__ part)
{
  const int c = blockIdx.x, b = blockIdx.y;
  const int t = threadIdx.x;
  const float* p = src + ((size_t)b * CH + c) * HW;
  float s = 0.f, s2 = 0.f;
  for (int i = t; i < HW; i += 256) {
    float v = p[i];
    s += v; s2 += v * v;
  }
  __shared__ float ls[256], ls2[256];
  ls[t] = s; ls2[t] = s2;
  __syncthreads();
  for (int off = 128; off > 0; off >>= 1) {
    if (t < off) { ls[t] += ls[t + off]; ls2[t] += ls2[t + off]; }
    __syncthreads();
  }
  if (t == 0) {
    part[((size_t)b * CH + c) * 2]     = ls[0];
    part[((size_t)b * CH + c) * 2 + 1] = ls2[0];
  }
}

// K3b: finalize: st[c] = mean, st[256+c] = rstd
__global__ __launch_bounds__(256) void stats_fin(
    const float* __restrict__ part, float* __restrict__ st)
{
  const int c = threadIdx.x;
  float s = 0.f, s2 = 0.f;
#pragma unroll
  for (int b = 0; b < BATCH; b++) {
    s  += part[((size_t)b * CH + c) * 2];
    s2 += part[((size_t)b * CH + c) * 2 + 1];
  }
  float m = s / (float)PTOT;
  float var = s2 / (float)PTOT - m * m;
  st[c] = m;
  st[CH + c] = rsqrtf(var + 1e-5f);
}

// ---------------------------------------------------------------------------
// K4: normalize out1 in place (-> xp NCHW f32) and write concat[P][256:512] bf16
// ---------------------------------------------------------------------------
__global__ __launch_bounds__(256) void norm_transpose(
    float* __restrict__ out1, const float* __restrict__ st,
    const float* __restrict__ g, const float* __restrict__ bb,
    u16* __restrict__ concat)
{
  __shared__ float tile[32][36];
  const int b  = blockIdx.z;
  const int c0 = blockIdx.y * 32;
  const int p0 = blockIdx.x * 32;
  int rem = HW - p0; if (rem > 32) rem = 32;
  const int t = threadIdx.x;

  {
    int c  = t >> 3;
    int p4 = (t & 7) * 4;
    int cg = c0 + c;
    float m  = st[cg], rs = st[CH + cg];
    float sc = g[cg] * rs;
    float sh = bb[cg] - m * sc;
    if (p4 < rem) {
      size_t base = ((size_t)b * CH + cg) * HW + p0;
      float4 v = *(const float4*)(out1 + base + p4);
      v.x = v.x * sc + sh; v.y = v.y * sc + sh;
      v.z = v.z * sc + sh; v.w = v.w * sc + sh;
      *(float4*)(out1 + base + p4) = v;
      *(float4*)&tile[c][p4] = v;
    }
  }
  __syncthreads();
  {
    int r  = t >> 3;
    int cq = (t & 7) * 4;
    if (r < rem) {
      us4 o;
      o.x = bf16_rne(tile[cq + 0][r]);
      o.y = bf16_rne(tile[cq + 1][r]);
      o.z = bf16_rne(tile[cq + 2][r]);
      o.w = bf16_rne(tile[cq + 3][r]);
      *(us4*)(concat + ((size_t)b * HW + p0 + r) * 512 + 256 + c0 + cq) = o;
    }
  }
}

// ---------------------------------------------------------------------------
// K5: offset conv via MFMA, tap-split 3-ways; XCD b-swizzled.
// ---------------------------------------------------------------------------
__global__ __launch_bounds__(128) void off_mfma(
    const u16* __restrict__ concat, const u16* __restrict__ wt_offb,
    float* __restrict__ offp3)
{
  const int t = threadIdx.x;
  const int g = blockIdx.y;
  const int wv = t >> 6, lane = t & 63;
  const int lr = lane & 15, lk = lane >> 4;
  const int id = blockIdx.x;
  const int b    = id & 7;
  const int tile = id >> 3;            // 0..112
  int pl = tile * 32 + wv * 16 + lr;   // 0..3615
  const bool pvalid = pl < HW;
  if (!pvalid) pl = HW - 1;
  const int P = b * HW + pl;
  const int h = pl / WW, w = pl - h * WW;

  f32x4 acc[2];
  acc[0] = (f32x4)0.f; acc[1] = (f32x4)0.f;

#pragma unroll 1
  for (int tl = 0; tl < 3; tl++) {
    int tap = g * 3 + tl;
    int dy = tap / 3 - 1, dx = tap % 3 - 1;
    bool valid = ((unsigned)(h + dy) < HH) && ((unsigned)(w + dx) < WW);
    int Ps = valid ? (P + dy * WW + dx) : P;
    const u16* bp = concat + (size_t)Ps * 512 + lk * 8;
    const u16* ap = wt_offb + ((size_t)tap * 32 + lr) * 512 + lk * 8;
#pragma unroll
    for (int cc = 0; cc < 16; cc++) {
      bf16x8 bfv = *(const bf16x8*)(bp + cc * 32);
      if (!valid) bfv = (bf16x8)(short)0;
      bf16x8 af0 = *(const bf16x8*)(ap + cc * 32);
      bf16x8 af1 = *(const bf16x8*)(ap + 16 * 512 + cc * 32);
      acc[0] = __builtin_amdgcn_mfma_f32_16x16x32_bf16(af0, bfv, acc[0], 0, 0, 0);
      acc[1] = __builtin_amdgcn_mfma_f32_16x16x32_bf16(af1, bfv, acc[1], 0, 0, 0);
    }
  }

  if (pvalid) {
#pragma unroll
    for (int mt = 0; mt < 2; mt++) {
      int oc = mt * 16 + lk * 4;
#pragma unroll
      for (int r = 0; r < 4; r++)
        offp3[((size_t)g * 32 + oc + r) * PTOT + P] = acc[mt][r];
    }
  }
}

// ---------------------------------------------------------------------------
// K6: finalize offsets -> bilinear params per (tap, P). Sums 3 tap-group partials.
// ---------------------------------------------------------------------------
__global__ __launch_bounds__(256) void off_finalize(
    const float* __restrict__ offp3, const float* __restrict__ off_b,
    float4* __restrict__ wts4, int4* __restrict__ idx4)
{
  int i = blockIdx.x * 256 + threadIdx.x;
  if (i >= 9 * PTOT) return;
  int k = i / PTOT;
  int P = i - k * PTOT;
  int b = P / HW;
  int p = P - b * HW;
  int h = p / WW;
  int w = p - h * WW;

  float dy = off_b[2 * k], dx = off_b[2 * k + 1], ml = off_b[18 + k];
#pragma unroll
  for (int g = 0; g < 3; g++) {
    const float* base = offp3 + (size_t)g * 32 * PTOT + P;
    dy += base[(size_t)(2 * k    ) * PTOT];
    dx += base[(size_t)(2 * k + 1) * PTOT];
    ml += base[(size_t)(18 + k   ) * PTOT];
  }

  float m = 1.f / (1.f + expf(-ml));
  float ph = dy + (float)(k / 3 - 1) + (float)h;
  float pw = dx + (float)(k % 3 - 1) + (float)w;
  float h0f = floorf(ph), w0f = floorf(pw);
  float lh = ph - h0f, lw = pw - w0f;
  int h0 = (int)h0f, w0 = (int)w0f;
  int h1 = h0 + 1, w1 = w0 + 1;
  float vh0 = (h0 >= 0 && h0 < HH) ? 1.f : 0.f;
  float vh1 = (h1 >= 0 && h1 < HH) ? 1.f : 0.f;
  float vw0 = (w0 >= 0 && w0 < WW) ? 1.f : 0.f;
  float vw1 = (w1 >= 0 && w1 < WW) ? 1.f : 0.f;
  float4 wv;
  wv.x = (1.f - lh) * (1.f - lw) * m * vh0 * vw0;
  wv.y = (1.f - lh) * lw         * m * vh0 * vw1;
  wv.z = lh * (1.f - lw)         * m * vh1 * vw0;
  wv.w = lh * lw                 * m * vh1 * vw1;
  int hc0 = min(max(h0, 0), HH - 1), hc1 = min(max(h1, 0), HH - 1);
  int wc0 = min(max(w0, 0), WW - 1), wc1 = min(max(w1, 0), WW - 1);
  int base = b * HW;
  int4 iv;
  iv.x = (base + hc0 * WW + wc0) * 512 + 256;
  iv.y = (base + hc0 * WW + wc1) * 512 + 256;
  iv.z = (base + hc1 * WW + wc0) * 512 + 256;
  iv.w = (base + hc1 * WW + wc1) * 512 + 256;
  wts4[i] = wv;
  idx4[i] = iv;
}

// ---------------------------------------------------------------------------
// K7: deformable conv via MFMA bf16 — R5 structure (best known: 114 us).
// Grid 456 = 8 b x 57 tiles of 64 pos (b = id&7 XCD swizzle).
// Block = 512 thr (8 waves); wave = 32 oc x 64 pos.
// Deltas vs R5: (1) bilinear params loaded directly per wave (wave-uniform,
// L1 broadcast) -> one barrier fewer per tap; (2) GEMM cc-loop unroll 2.
// ---------------------------------------------------------------------------
__global__ __launch_bounds__(512) void deform_mfma(
    const u16* __restrict__ concat,
    const float4* __restrict__ wts4, const int4* __restrict__ idx4,
    const u16* __restrict__ wt_b,
    float* __restrict__ d)
{
  __shared__ u16 samp[64 * 256];   // swizzled: byte ^= (pos&7)<<4

  const int t    = threadIdx.x;
  const int wv   = t >> 6;           // 0..7
  const int lane = t & 63;
  const int lr = lane & 15, lk = lane >> 4;
  const int id   = blockIdx.x;
  const int b    = id & 7;
  const int tile = id >> 3;          // 0..56
  const int P0   = b * HW + tile * 64;
  int lim  = HW - tile * 64;
  if (lim > 64) lim = 64;

  f32x4 acc[2][4];
#pragma unroll
  for (int mt = 0; mt < 2; mt++)
#pragma unroll
    for (int nt = 0; nt < 4; nt++) acc[mt][nt] = (f32x4)0.f;

  const int c4 = lane * 4;

  for (int tap = 0; tap < 9; tap++) {
    __syncthreads();   // prev GEMM done reading samp

    // build samp: 8 iters, one pos per wave per iter; params direct-loaded
#pragma unroll 2
    for (int it = 0; it < 8; it++) {
      int pos = it * 8 + wv;
      int off = pos < lim ? pos : lim - 1;
      const int4   iv = idx4[(size_t)tap * PTOT + P0 + off];
      const float4 wq = wts4[(size_t)tap * PTOT + P0 + off];
      uint2 u0 = *(const uint2*)(concat + iv.x + c4);
      uint2 u1 = *(const uint2*)(concat + iv.y + c4);
      uint2 u2 = *(const uint2*)(concat + iv.z + c4);
      uint2 u3 = *(const uint2*)(concat + iv.w + c4);
      float a0, a1, a2, a3;
      a0  = wq.x * __uint_as_float(u0.x << 16);
      a1  = wq.x * __uint_as_float(u0.x & 0xFFFF0000u);
      a2  = wq.x * __uint_as_float(u0.y << 16);
      a3  = wq.x * __uint_as_float(u0.y & 0xFFFF0000u);
      a0 = fmaf(wq.y, __uint_as_float(u1.x << 16), a0);
      a1 = fmaf(wq.y, __uint_as_float(u1.x & 0xFFFF0000u), a1);
      a2 = fmaf(wq.y, __uint_as_float(u1.y << 16), a2);
      a3 = fmaf(wq.y, __uint_as_float(u1.y & 0xFFFF0000u), a3);
      a0 = fmaf(wq.z, __uint_as_float(u2.x << 16), a0);
      a1 = fmaf(wq.z, __uint_as_float(u2.x & 0xFFFF0000u), a1);
      a2 = fmaf(wq.z, __uint_as_float(u2.y << 16), a2);
      a3 = fmaf(wq.z, __uint_as_float(u2.y & 0xFFFF0000u), a3);
      a0 = fmaf(wq.w, __uint_as_float(u3.x << 16), a0);
      a1 = fmaf(wq.w, __uint_as_float(u3.x & 0xFFFF0000u), a1);
      a2 = fmaf(wq.w, __uint_as_float(u3.y << 16), a2);
      a3 = fmaf(wq.w, __uint_as_float(u3.y & 0xFFFF0000u), a3);
      uint2 r;
      r.x = (__float_as_uint(a0) >> 16) | (__float_as_uint(a1) & 0xFFFF0000u);
      r.y = (__float_as_uint(a2) >> 16) | (__float_as_uint(a3) & 0xFFFF0000u);
      u32 byte = (u32)pos * 512u + (u32)c4 * 2u;
      byte ^= (u32)(pos & 7) << 4;
      *(uint2*)((char*)samp + byte) = r;
    }
    __syncthreads();   // samp ready

    // GEMM: 8 K-chunks of 32 channels
#pragma unroll 2
    for (int cc = 0; cc < 8; cc++) {
      int c0 = cc * 32;
      bf16x8 bfr[4];
#pragma unroll
      for (int nt = 0; nt < 4; nt++) {
        int pos = nt * 16 + lr;
        u32 byte = (u32)pos * 512u + (u32)(c0 + lk * 8) * 2u;
        byte ^= (u32)(pos & 7) << 4;
        bfr[nt] = *(const bf16x8*)((const char*)samp + byte);
      }
      const u16* wp = wt_b + ((size_t)tap * 256 + wv * 32 + lr) * 256
                      + c0 + lk * 8;
      bf16x8 afr[2];
#pragma unroll
      for (int mt = 0; mt < 2; mt++)
        afr[mt] = *(const bf16x8*)(wp + (size_t)mt * 16 * 256);
#pragma unroll
      for (int mt = 0; mt < 2; mt++)
#pragma unroll
        for (int nt = 0; nt < 4; nt++)
          acc[mt][nt] = __builtin_amdgcn_mfma_f32_16x16x32_bf16(
              afr[mt], bfr[nt], acc[mt][nt], 0, 0, 0);
    }
  }

  // epilogue: D[oc][pos] -> d NCHW
#pragma unroll
  for (int mt = 0; mt < 2; mt++) {
    int oc = wv * 32 + mt * 16 + lk * 4;
#pragma unroll
    for (int nt = 0; nt < 4; nt++) {
      int pl = tile * 64 + nt * 16 + lr;
      if (pl < HW) {
        float* dst = d + ((size_t)(b * CH + oc)) * HW + pl;
#pragma unroll
        for (int r = 0; r < 4; r++)
          dst[(size_t)r * HW] = acc[mt][nt][r];
      }
    }
  }
}

// ---------------------------------------------------------------------------
// K8: final = relu(d*sc + sh + xp), all NCHW, elementwise float4
// ---------------------------------------------------------------------------
__global__ __launch_bounds__(256) void final_nchw(
    const float* __restrict__ d, const float* __restrict__ xp,
    const float* __restrict__ st2, const float* __restrict__ ng,
    const float* __restrict__ nb, float* __restrict__ out)
{
  u32 i4 = blockIdx.x * 256 + threadIdx.x;
  u32 e = i4 * 4;
  int row = (int)(e / HW);
  int c = row & 255;
  float m = st2[c], rs = st2[CH + c];
  float sc = ng[c] * rs;
  float sh = nb[c] - m * sc;
  float4 dv = *(const float4*)(d + e);
  float4 xv = *(const float4*)(xp + e);
  float4 o;
  o.x = dv.x * sc + sh + xv.x;
  o.y = dv.y * sc + sh + xv.y;
  o.z = dv.z * sc + sh + xv.z;
  o.w = dv.w * sc + sh + xv.w;
  o.x = o.x > 0.f ? o.x : 0.f;
  o.y = o.y > 0.f ? o.y : 0.f;
  o.z = o.z > 0.f ? o.z : 0.f;
  o.w = o.w > 0.f ? o.w : 0.f;
  *(float4*)(out + e) = o;
}

// ---------------------------------------------------------------------------
extern "C" void kernel_launch(void* const* d_in, const int* in_sizes, int n_in,
                              void* d_out, int out_size, void* d_ws, size_t ws_size,
                              hipStream_t stream)
{
  const float* x       = (const float*)d_in[0];
  const float* conv1_w = (const float*)d_in[1];
  const float* bn1_g   = (const float*)d_in[2];
  const float* bn1_b   = (const float*)d_in[3];
  const float* off_w   = (const float*)d_in[4];
  const float* off_b   = (const float*)d_in[5];
  const float* dcn_w   = (const float*)d_in[6];
  const float* norm_g  = (const float*)d_in[8];
  const float* norm_b  = (const float*)d_in[9];
  float* out = (float*)d_out;

  char* ws = (char*)d_ws;
  size_t o = 0;
  float* out1    = (float*)(ws + o); o += (size_t)PTOT * CH * 4;       // 29.5 MB (becomes xp NCHW)
  u16*   concat  = (u16*)  (ws + o); o += (size_t)PTOT * 512 * 2;      // 29.5 MB NHWC bf16 [flipx | xp]
  float* dbuf    = (float*)(ws + o); o += (size_t)PTOT * CH * 4;       // 29.5 MB NCHW
  float* offp3   = (float*)(ws + o); o += (size_t)96 * PTOT * 4;       // 11.1 MB
  u16*   wt_b    = (u16*)  (ws + o); o += (size_t)9 * 256 * 256 * 2;   // 1.18 MB
  u16*   wt_offb = (u16*)  (ws + o); o += (size_t)9 * 32 * 512 * 2;    // 0.29 MB
  u16*   w1b     = (u16*)  (ws + o); o += (size_t)256 * 256 * 2;       // 0.13 MB
  float4* wts4   = (float4*)(ws + o); o += (size_t)9 * PTOT * 16;      // 4.15 MB
  int4*   idx4   = (int4*) (ws + o); o += (size_t)9 * PTOT * 16;       // 4.15 MB
  float* st      = (float*)(ws + o); o += 512 * 4;
  float* st2     = (float*)(ws + o); o += 512 * 4;
  float* part    = (float*)(ws + o); o += (size_t)BATCH * CH * 2 * 4;  // 16 KB

  prep_wts<<<2304, 256, 0, stream>>>(conv1_w, off_w, dcn_w, w1b, wt_offb, wt_b);
  flip_transpose<<<dim3(113, 8, 8), 256, 0, stream>>>(x, concat);
  conv1_mfma<<<dim3(232, 2), 256, 0, stream>>>(concat, w1b, out1);
  stats_part<<<dim3(256, 8), 256, 0, stream>>>(out1, part);
  stats_fin<<<1, 256, 0, stream>>>(part, st);
  norm_transpose<<<dim3(113, 8, 8), 256, 0, stream>>>(out1, st, bn1_g, bn1_b, concat);
  off_mfma<<<dim3(904, 3), 128, 0, stream>>>(concat, wt_offb, offp3);
  off_finalize<<<(9 * PTOT + 255) / 256, 256, 0, stream>>>(offp3, off_b, wts4, idx4);
  deform_mfma<<<456, 512, 0, stream>>>(concat, wts4, idx4, wt_b, dbuf);
  stats_part<<<dim3(256, 8), 256, 0, stream>>>(dbuf, part);
  stats_fin<<<1, 256, 0, stream>>>(part, st2);
  final_nchw<<<7200, 256, 0, stream>>>(dbuf, out1, st2, norm_g, norm_b, out);
}

// Round 10
// 281.718 us; speedup vs baseline: 1.7761x; 1.0771x over previous
//
#include <hip/hip_runtime.h>
#include <math.h>

// Problem constants
#define BATCH 8
#define CH 256
#define HH 45
#define WW 80
#define HW 3600        // 45*80
#define PTOT 28800     // BATCH*HW

typedef unsigned short u16;
typedef unsigned int   u32;
typedef __attribute__((ext_vector_type(8))) short bf16x8;
typedef __attribute__((ext_vector_type(4))) float f32x4;

struct __align__(8) us4 { u16 x, y, z, w; };

__device__ __forceinline__ u16 bf16_rne(float x) {
  u32 u = __float_as_uint(x);
  u += 0x7FFF + ((u >> 16) & 1);
  return (u16)(u >> 16);
}

// ---------------------------------------------------------------------------
// K0: weight prep (all bf16 transposes)
// ---------------------------------------------------------------------------
__global__ __launch_bounds__(256) void prep_wts(
    const float* __restrict__ conv1_w, const float* __restrict__ off_w,
    const float* __restrict__ dcn_w,
    u16* __restrict__ w1b, u16* __restrict__ wt_offb, u16* __restrict__ wt_b)
{
  int i = blockIdx.x * 256 + threadIdx.x;
  if (i < 256 * 256) {
    w1b[i] = bf16_rne(conv1_w[i]);
  }
  if (i < 9 * 32 * 512) {
    int tap = i >> 14;
    int r   = i & 16383;
    int oc  = r >> 9;
    int c   = r & 511;
    float v = (oc < 27) ? off_w[((size_t)oc * 512 + c) * 9 + tap] : 0.f;
    wt_offb[i] = bf16_rne(v);
  }
  if (i < 9 * 256 * 256) {
    int c = i & 255;
    int oc = (i >> 8) & 255;
    int tap = i >> 16;
    wt_b[i] = bf16_rne(dcn_w[((size_t)oc * 256 + c) * 9 + tap]);
  }
}

// ---------------------------------------------------------------------------
// K1: flip-transpose x -> concat[P][0:256] bf16 (w-flipped NHWC)
// ---------------------------------------------------------------------------
__global__ __launch_bounds__(256) void flip_transpose(
    const float* __restrict__ x, u16* __restrict__ concat)
{
  __shared__ float tile[32][36];
  const int b  = blockIdx.z;
  const int c0 = blockIdx.y * 32;
  const int p0 = blockIdx.x * 32;
  int rem = HW - p0; if (rem > 32) rem = 32;
  const int t = threadIdx.x;
  {
    int c = t >> 3, p4 = (t & 7) * 4;
    if (p4 < rem) {
      float4 v = *(const float4*)(x + ((size_t)b * CH + c0 + c) * HW + p0 + p4);
      *(float4*)&tile[c][p4] = v;
    }
  }
  __syncthreads();
  {
    int r = t >> 3, cq = (t & 7) * 4;
    if (r < rem) {
      int p = p0 + r;
      int h = p / WW, w = p - h * WW;
      int pf = h * WW + (WW - 1 - w);
      us4 o;
      o.x = bf16_rne(tile[cq + 0][r]);
      o.y = bf16_rne(tile[cq + 1][r]);
      o.z = bf16_rne(tile[cq + 2][r]);
      o.w = bf16_rne(tile[cq + 3][r]);
      *(us4*)(concat + ((size_t)b * HW + pf) * 512 + c0 + cq) = o;
    }
  }
}

// ---------------------------------------------------------------------------
// K2: conv1 via MFMA, XCD b-swizzled: grid (232 = 8b x 29 ptiles, 2 octiles).
// ---------------------------------------------------------------------------
__global__ __launch_bounds__(256) void conv1_mfma(
    const u16* __restrict__ concat, const u16* __restrict__ w1b,
    float* __restrict__ out1)
{
  const int t = threadIdx.x;
  const int wv = t >> 6, lane = t & 63;
  const int lr = lane & 15, lk = lane >> 4;
  const int id = blockIdx.x;
  const int b  = id & 7;
  const int pt = id >> 3;                    // 0..28
  const int oc0 = blockIdx.y * 128 + (wv & 1) * 64;
  const int p0  = pt * 128 + (wv >> 1) * 64; // within image

  const u16* bptr[4];
#pragma unroll
  for (int nt = 0; nt < 4; nt++) {
    int pl = p0 + nt * 16 + lr;
    int pc = pl < HW ? pl : HW - 1;
    int h = pc / WW, w = pc - h * WW;
    int pf = b * HW + h * WW + (WW - 1 - w);
    bptr[nt] = concat + (size_t)pf * 512 + lk * 8;
  }
  const u16* aptr = w1b + ((size_t)(oc0 + lr)) * 256 + lk * 8;

  f32x4 acc[4][4];
#pragma unroll
  for (int mt = 0; mt < 4; mt++)
#pragma unroll
    for (int nt = 0; nt < 4; nt++) acc[mt][nt] = (f32x4)0.f;

#pragma unroll
  for (int cc = 0; cc < 8; cc++) {
    bf16x8 af[4], bfv[4];
#pragma unroll
    for (int mt = 0; mt < 4; mt++)
      af[mt] = *(const bf16x8*)(aptr + (size_t)mt * 16 * 256 + cc * 32);
#pragma unroll
    for (int nt = 0; nt < 4; nt++)
      bfv[nt] = *(const bf16x8*)(bptr[nt] + cc * 32);
#pragma unroll
    for (int mt = 0; mt < 4; mt++)
#pragma unroll
      for (int nt = 0; nt < 4; nt++)
        acc[mt][nt] = __builtin_amdgcn_mfma_f32_16x16x32_bf16(
            af[mt], bfv[nt], acc[mt][nt], 0, 0, 0);
  }

#pragma unroll
  for (int mt = 0; mt < 4; mt++) {
    int oc = oc0 + mt * 16 + lk * 4;
#pragma unroll
    for (int nt = 0; nt < 4; nt++) {
      int pl = p0 + nt * 16 + lr;
      if (pl < HW) {
        float* dst = out1 + ((size_t)(b * CH + oc)) * HW + pl;
#pragma unroll
        for (int r = 0; r < 4; r++)
          dst[(size_t)r * HW] = acc[mt][nt][r];
      }
    }
  }
}

// ---------------------------------------------------------------------------
// K3a: per-(c,b)-plane partial sums. grid (256, 8).
// ---------------------------------------------------------------------------
__global__ __launch_bounds__(256) void stats_part(
    const float* __restrict__ src, float* __restrict__ part)
{
  const int c = blockIdx.x, b = blockIdx.y;
  const int t = threadIdx.x;
  const float* p = src + ((size_t)b * CH + c) * HW;
  float s = 0.f, s2 = 0.f;
  for (int i = t; i < HW; i += 256) {
    float v = p[i];
    s += v; s2 += v * v;
  }
  __shared__ float ls[256], ls2[256];
  ls[t] = s; ls2[t] = s2;
  __syncthreads();
  for (int off = 128; off > 0; off >>= 1) {
    if (t < off) { ls[t] += ls[t + off]; ls2[t] += ls2[t + off]; }
    __syncthreads();
  }
  if (t == 0) {
    part[((size_t)b * CH + c) * 2]     = ls[0];
    part[((size_t)b * CH + c) * 2 + 1] = ls2[0];
  }
}

// K3b: finalize: st[c] = mean, st[256+c] = rstd
__global__ __launch_bounds__(256) void stats_fin(
    const float* __restrict__ part, float* __restrict__ st)
{
  const int c = threadIdx.x;
  float s = 0.f, s2 = 0.f;
#pragma unroll
  for (int b = 0; b < BATCH; b++) {
    s  += part[((size_t)b * CH + c) * 2];
    s2 += part[((size_t)b * CH + c) * 2 + 1];
  }
  float m = s / (float)PTOT;
  float var = s2 / (float)PTOT - m * m;
  st[c] = m;
  st[CH + c] = rsqrtf(var + 1e-5f);
}

// ---------------------------------------------------------------------------
// K4: read RAW out1, write normalized bf16 into concat[P][256:512].
// out1 stays raw (final_nchw re-applies the affine on the fly).
// ---------------------------------------------------------------------------
__global__ __launch_bounds__(256) void norm_transpose(
    const float* __restrict__ out1, const float* __restrict__ st,
    const float* __restrict__ g, const float* __restrict__ bb,
    u16* __restrict__ concat)
{
  __shared__ float tile[32][36];
  const int b  = blockIdx.z;
  const int c0 = blockIdx.y * 32;
  const int p0 = blockIdx.x * 32;
  int rem = HW - p0; if (rem > 32) rem = 32;
  const int t = threadIdx.x;

  {
    int c  = t >> 3;
    int p4 = (t & 7) * 4;
    int cg = c0 + c;
    float m  = st[cg], rs = st[CH + cg];
    float sc = g[cg] * rs;
    float sh = bb[cg] - m * sc;
    if (p4 < rem) {
      size_t base = ((size_t)b * CH + cg) * HW + p0;
      float4 v = *(const float4*)(out1 + base + p4);
      v.x = v.x * sc + sh; v.y = v.y * sc + sh;
      v.z = v.z * sc + sh; v.w = v.w * sc + sh;
      *(float4*)&tile[c][p4] = v;
    }
  }
  __syncthreads();
  {
    int r  = t >> 3;
    int cq = (t & 7) * 4;
    if (r < rem) {
      us4 o;
      o.x = bf16_rne(tile[cq + 0][r]);
      o.y = bf16_rne(tile[cq + 1][r]);
      o.z = bf16_rne(tile[cq + 2][r]);
      o.w = bf16_rne(tile[cq + 3][r]);
      *(us4*)(concat + ((size_t)b * HW + p0 + r) * 512 + 256 + c0 + cq) = o;
    }
  }
}

// ---------------------------------------------------------------------------
// K5: offset conv via MFMA, tap-split 3-ways; XCD b-swizzled.
// ---------------------------------------------------------------------------
__global__ __launch_bounds__(128) void off_mfma(
    const u16* __restrict__ concat, const u16* __restrict__ wt_offb,
    float* __restrict__ offp3)
{
  const int t = threadIdx.x;
  const int g = blockIdx.y;
  const int wv = t >> 6, lane = t & 63;
  const int lr = lane & 15, lk = lane >> 4;
  const int id = blockIdx.x;
  const int b    = id & 7;
  const int tile = id >> 3;            // 0..112
  int pl = tile * 32 + wv * 16 + lr;   // 0..3615
  const bool pvalid = pl < HW;
  if (!pvalid) pl = HW - 1;
  const int P = b * HW + pl;
  const int h = pl / WW, w = pl - h * WW;

  f32x4 acc[2];
  acc[0] = (f32x4)0.f; acc[1] = (f32x4)0.f;

#pragma unroll 1
  for (int tl = 0; tl < 3; tl++) {
    int tap = g * 3 + tl;
    int dy = tap / 3 - 1, dx = tap % 3 - 1;
    bool valid = ((unsigned)(h + dy) < HH) && ((unsigned)(w + dx) < WW);
    int Ps = valid ? (P + dy * WW + dx) : P;
    const u16* bp = concat + (size_t)Ps * 512 + lk * 8;
    const u16* ap = wt_offb + ((size_t)tap * 32 + lr) * 512 + lk * 8;
#pragma unroll
    for (int cc = 0; cc < 16; cc++) {
      bf16x8 bfv = *(const bf16x8*)(bp + cc * 32);
      if (!valid) bfv = (bf16x8)(short)0;
      bf16x8 af0 = *(const bf16x8*)(ap + cc * 32);
      bf16x8 af1 = *(const bf16x8*)(ap + 16 * 512 + cc * 32);
      acc[0] = __builtin_amdgcn_mfma_f32_16x16x32_bf16(af0, bfv, acc[0], 0, 0, 0);
      acc[1] = __builtin_amdgcn_mfma_f32_16x16x32_bf16(af1, bfv, acc[1], 0, 0, 0);
    }
  }

  if (pvalid) {
#pragma unroll
    for (int mt = 0; mt < 2; mt++) {
      int oc = mt * 16 + lk * 4;
#pragma unroll
      for (int r = 0; r < 4; r++)
        offp3[((size_t)g * 32 + oc + r) * PTOT + P] = acc[mt][r];
    }
  }
}

// ---------------------------------------------------------------------------
// K6: finalize offsets -> bilinear params per (tap, P). Sums 3 tap-group partials.
// ---------------------------------------------------------------------------
__global__ __launch_bounds__(256) void off_finalize(
    const float* __restrict__ offp3, const float* __restrict__ off_b,
    float4* __restrict__ wts4, int4* __restrict__ idx4)
{
  int i = blockIdx.x * 256 + threadIdx.x;
  if (i >= 9 * PTOT) return;
  int k = i / PTOT;
  int P = i - k * PTOT;
  int b = P / HW;
  int p = P - b * HW;
  int h = p / WW;
  int w = p - h * WW;

  float dy = off_b[2 * k], dx = off_b[2 * k + 1], ml = off_b[18 + k];
#pragma unroll
  for (int g = 0; g < 3; g++) {
    const float* base = offp3 + (size_t)g * 32 * PTOT + P;
    dy += base[(size_t)(2 * k    ) * PTOT];
    dx += base[(size_t)(2 * k + 1) * PTOT];
    ml += base[(size_t)(18 + k   ) * PTOT];
  }

  float m = 1.f / (1.f + expf(-ml));
  float ph = dy + (float)(k / 3 - 1) + (float)h;
  float pw = dx + (float)(k % 3 - 1) + (float)w;
  float h0f = floorf(ph), w0f = floorf(pw);
  float lh = ph - h0f, lw = pw - w0f;
  int h0 = (int)h0f, w0 = (int)w0f;
  int h1 = h0 + 1, w1 = w0 + 1;
  float vh0 = (h0 >= 0 && h0 < HH) ? 1.f : 0.f;
  float vh1 = (h1 >= 0 && h1 < HH) ? 1.f : 0.f;
  float vw0 = (w0 >= 0 && w0 < WW) ? 1.f : 0.f;
  float vw1 = (w1 >= 0 && w1 < WW) ? 1.f : 0.f;
  float4 wv;
  wv.x = (1.f - lh) * (1.f - lw) * m * vh0 * vw0;
  wv.y = (1.f - lh) * lw         * m * vh0 * vw1;
  wv.z = lh * (1.f - lw)         * m * vh1 * vw0;
  wv.w = lh * lw                 * m * vh1 * vw1;
  int hc0 = min(max(h0, 0), HH - 1), hc1 = min(max(h1, 0), HH - 1);
  int wc0 = min(max(w0, 0), WW - 1), wc1 = min(max(w1, 0), WW - 1);
  int base = b * HW;
  int4 iv;
  iv.x = (base + hc0 * WW + wc0) * 512 + 256;
  iv.y = (base + hc0 * WW + wc1) * 512 + 256;
  iv.z = (base + hc1 * WW + wc0) * 512 + 256;
  iv.w = (base + hc1 * WW + wc1) * 512 + 256;
  wts4[i] = wv;
  idx4[i] = iv;
}

// ---------------------------------------------------------------------------
// K7: deformable conv via MFMA bf16 — EXACT R5 structure (best known: 114 us).
// Grid 456 = 8 b x 57 tiles of 64 pos (b = id&7 XCD swizzle).
// Block = 512 thr (8 waves); wave = 32 oc x 64 pos.
// ---------------------------------------------------------------------------
__global__ __launch_bounds__(512) void deform_mfma(
    const u16* __restrict__ concat,
    const float4* __restrict__ wts4, const int4* __restrict__ idx4,
    const u16* __restrict__ wt_b,
    float* __restrict__ d)
{
  __shared__ u16   samp[64 * 256];   // swizzled: byte ^= (pos&7)<<4
  __shared__ float4 sw4[64];
  __shared__ int4   sidx4[64];

  const int t    = threadIdx.x;
  const int wv   = t >> 6;           // 0..7
  const int lane = t & 63;
  const int lr = lane & 15, lk = lane >> 4;
  const int id   = blockIdx.x;
  const int b    = id & 7;
  const int tile = id >> 3;          // 0..56
  const int P0   = b * HW + tile * 64;
  int lim  = HW - tile * 64;         // valid positions in this tile (<=64)
  if (lim > 64) lim = 64;

  f32x4 acc[2][4];
#pragma unroll
  for (int mt = 0; mt < 2; mt++)
#pragma unroll
    for (int nt = 0; nt < 4; nt++) acc[mt][nt] = (f32x4)0.f;

  const int c4 = lane * 4;

  for (int tap = 0; tap < 9; tap++) {
    __syncthreads();
    if (t < 64) {
      int off = (t < lim) ? t : (lim - 1);
      sw4[t]   = wts4[(size_t)tap * PTOT + P0 + off];
      sidx4[t] = idx4[(size_t)tap * PTOT + P0 + off];
    }
    __syncthreads();

    // build samp: 8 iters, each wave one pos per iter
#pragma unroll 2
    for (int it = 0; it < 8; it++) {
      int pos = it * 8 + wv;
      int4  iv = sidx4[pos];
      float4 wq = sw4[pos];
      uint2 u0 = *(const uint2*)(concat + iv.x + c4);
      uint2 u1 = *(const uint2*)(concat + iv.y + c4);
      uint2 u2 = *(const uint2*)(concat + iv.z + c4);
      uint2 u3 = *(const uint2*)(concat + iv.w + c4);
      float a0, a1, a2, a3;
      a0  = wq.x * __uint_as_float(u0.x << 16);
      a1  = wq.x * __uint_as_float(u0.x & 0xFFFF0000u);
      a2  = wq.x * __uint_as_float(u0.y << 16);
      a3  = wq.x * __uint_as_float(u0.y & 0xFFFF0000u);
      a0 = fmaf(wq.y, __uint_as_float(u1.x << 16), a0);
      a1 = fmaf(wq.y, __uint_as_float(u1.x & 0xFFFF0000u), a1);
      a2 = fmaf(wq.y, __uint_as_float(u1.y << 16), a2);
      a3 = fmaf(wq.y, __uint_as_float(u1.y & 0xFFFF0000u), a3);
      a0 = fmaf(wq.z, __uint_as_float(u2.x << 16), a0);
      a1 = fmaf(wq.z, __uint_as_float(u2.x & 0xFFFF0000u), a1);
      a2 = fmaf(wq.z, __uint_as_float(u2.y << 16), a2);
      a3 = fmaf(wq.z, __uint_as_float(u2.y & 0xFFFF0000u), a3);
      a0 = fmaf(wq.w, __uint_as_float(u3.x << 16), a0);
      a1 = fmaf(wq.w, __uint_as_float(u3.x & 0xFFFF0000u), a1);
      a2 = fmaf(wq.w, __uint_as_float(u3.y << 16), a2);
      a3 = fmaf(wq.w, __uint_as_float(u3.y & 0xFFFF0000u), a3);
      uint2 r;
      r.x = (__float_as_uint(a0) >> 16) | (__float_as_uint(a1) & 0xFFFF0000u);
      r.y = (__float_as_uint(a2) >> 16) | (__float_as_uint(a3) & 0xFFFF0000u);
      u32 byte = (u32)pos * 512u + (u32)c4 * 2u;
      byte ^= (u32)(pos & 7) << 4;
      *(uint2*)((char*)samp + byte) = r;
    }
    __syncthreads();

#pragma unroll 1
    for (int cc = 0; cc < 8; cc++) {
      int c0 = cc * 32;
      bf16x8 bfr[4];
#pragma unroll
      for (int nt = 0; nt < 4; nt++) {
        int pos = nt * 16 + lr;
        u32 byte = (u32)pos * 512u + (u32)(c0 + lk * 8) * 2u;
        byte ^= (u32)(pos & 7) << 4;
        bfr[nt] = *(const bf16x8*)((const char*)samp + byte);
      }
      const u16* wp = wt_b + ((size_t)tap * 256 + wv * 32 + lr) * 256
                      + c0 + lk * 8;
      bf16x8 afr[2];
#pragma unroll
      for (int mt = 0; mt < 2; mt++)
        afr[mt] = *(const bf16x8*)(wp + (size_t)mt * 16 * 256);
#pragma unroll
      for (int mt = 0; mt < 2; mt++)
#pragma unroll
        for (int nt = 0; nt < 4; nt++)
          acc[mt][nt] = __builtin_amdgcn_mfma_f32_16x16x32_bf16(
              afr[mt], bfr[nt], acc[mt][nt], 0, 0, 0);
    }
  }

  // epilogue: D[oc][pos] -> d NCHW
#pragma unroll
  for (int mt = 0; mt < 2; mt++) {
    int oc = wv * 32 + mt * 16 + lk * 4;
#pragma unroll
    for (int nt = 0; nt < 4; nt++) {
      int pl = tile * 64 + nt * 16 + lr;
      if (pl < HW) {
        float* dst = d + ((size_t)(b * CH + oc)) * HW + pl;
#pragma unroll
        for (int r = 0; r < 4; r++)
          dst[(size_t)r * HW] = acc[mt][nt][r];
      }
    }
  }
}

// ---------------------------------------------------------------------------
// K8: final = relu(d*sc2+sh2 + (out1raw*sc1+sh1)), all NCHW, float4.
// bn1 affine applied on the fly (out1 stays raw; saves a 29.5 MB write).
// ---------------------------------------------------------------------------
__global__ __launch_bounds__(256) void final_nchw(
    const float* __restrict__ d, const float* __restrict__ out1raw,
    const float* __restrict__ st1, const float* __restrict__ g1,
    const float* __restrict__ b1,
    const float* __restrict__ st2, const float* __restrict__ g2,
    const float* __restrict__ b2, float* __restrict__ out)
{
  u32 i4 = blockIdx.x * 256 + threadIdx.x;
  u32 e = i4 * 4;
  int row = (int)(e / HW);
  int c = row & 255;
  float m1 = st1[c], rs1 = st1[CH + c];
  float sc1 = g1[c] * rs1;
  float sh1 = b1[c] - m1 * sc1;
  float m2 = st2[c], rs2 = st2[CH + c];
  float sc2 = g2[c] * rs2;
  float sh2 = b2[c] - m2 * sc2;
  float4 dv = *(const float4*)(d + e);
  float4 xv = *(const float4*)(out1raw + e);
  float4 o;
  o.x = dv.x * sc2 + sh2 + xv.x * sc1 + sh1;
  o.y = dv.y * sc2 + sh2 + xv.y * sc1 + sh1;
  o.z = dv.z * sc2 + sh2 + xv.z * sc1 + sh1;
  o.w = dv.w * sc2 + sh2 + xv.w * sc1 + sh1;
  o.x = o.x > 0.f ? o.x : 0.f;
  o.y = o.y > 0.f ? o.y : 0.f;
  o.z = o.z > 0.f ? o.z : 0.f;
  o.w = o.w > 0.f ? o.w : 0.f;
  *(float4*)(out + e) = o;
}

// ---------------------------------------------------------------------------
extern "C" void kernel_launch(void* const* d_in, const int* in_sizes, int n_in,
                              void* d_out, int out_size, void* d_ws, size_t ws_size,
                              hipStream_t stream)
{
  const float* x       = (const float*)d_in[0];
  const float* conv1_w = (const float*)d_in[1];
  const float* bn1_g   = (const float*)d_in[2];
  const float* bn1_b   = (const float*)d_in[3];
  const float* off_w   = (const float*)d_in[4];
  const float* off_b   = (const float*)d_in[5];
  const float* dcn_w   = (const float*)d_in[6];
  const float* norm_g  = (const float*)d_in[8];
  const float* norm_b  = (const float*)d_in[9];
  float* out = (float*)d_out;

  char* ws = (char*)d_ws;
  size_t o = 0;
  float* out1    = (float*)(ws + o); o += (size_t)PTOT * CH * 4;       // 29.5 MB (RAW conv1 output)
  u16*   concat  = (u16*)  (ws + o); o += (size_t)PTOT * 512 * 2;      // 29.5 MB NHWC bf16 [flipx | xp]
  float* dbuf    = (float*)(ws + o); o += (size_t)PTOT * CH * 4;       // 29.5 MB NCHW
  float* offp3   = (float*)(ws + o); o += (size_t)96 * PTOT * 4;       // 11.1 MB
  u16*   wt_b    = (u16*)  (ws + o); o += (size_t)9 * 256 * 256 * 2;   // 1.18 MB
  u16*   wt_offb = (u16*)  (ws + o); o += (size_t)9 * 32 * 512 * 2;    // 0.29 MB
  u16*   w1b     = (u16*)  (ws + o); o += (size_t)256 * 256 * 2;       // 0.13 MB
  float4* wts4   = (float4*)(ws + o); o += (size_t)9 * PTOT * 16;      // 4.15 MB
  int4*   idx4   = (int4*) (ws + o); o += (size_t)9 * PTOT * 16;       // 4.15 MB
  float* st      = (float*)(ws + o); o += 512 * 4;
  float* st2     = (float*)(ws + o); o += 512 * 4;
  float* part    = (float*)(ws + o); o += (size_t)BATCH * CH * 2 * 4;  // 16 KB

  prep_wts<<<2304, 256, 0, stream>>>(conv1_w, off_w, dcn_w, w1b, wt_offb, wt_b);
  flip_transpose<<<dim3(113, 8, 8), 256, 0, stream>>>(x, concat);
  conv1_mfma<<<dim3(232, 2), 256, 0, stream>>>(concat, w1b, out1);
  stats_part<<<dim3(256, 8), 256, 0, stream>>>(out1, part);
  stats_fin<<<1, 256, 0, stream>>>(part, st);
  norm_transpose<<<dim3(113, 8, 8), 256, 0, stream>>>(out1, st, bn1_g, bn1_b, concat);
  off_mfma<<<dim3(904, 3), 128, 0, stream>>>(concat, wt_offb, offp3);
  off_finalize<<<(9 * PTOT + 255) / 256, 256, 0, stream>>>(offp3, off_b, wts4, idx4);
  deform_mfma<<<456, 512, 0, stream>>>(concat, wts4, idx4, wt_b, dbuf);
  stats_part<<<dim3(256, 8), 256, 0, stream>>>(dbuf, part);
  stats_fin<<<1, 256, 0, stream>>>(part, st2);
  final_nchw<<<7200, 256, 0, stream>>>(dbuf, out1, st, bn1_g, bn1_b,
                                       st2, norm_g, norm_b, out);
}